// Round 11
// baseline (239.811 us; speedup 1.0000x reference)
//
#include <hip/hip_runtime.h>
#include <cstdint>

typedef unsigned long long u64;
typedef unsigned int u32;

#define B_ 4
#define N_ 3600
#define C_ 16
#define NW_ 57        // ceil(N/64) words of adjacency/valid bitmask
#define NPAD_ 3648    // NW_*64
#define RPW_ 4        // rows per wave (k_adjcon)
#define RPB_ 16       // rows per block (k_adjcon, 4 waves)
#define HW0_ 1856     // j-half 0: words 0..28  (29 words)
#define HW1_ 1792     // j-half 1: words 29..56 (28 words)
#define NBLK_ 15      // k_valid: blocks per image (15*256 = 3840 >= N)
#define CH_ 64        // greedy chunk size

// ---------------------------------------------------------------------------
// K1: adjacency bitmask + fused threshold (old k_adj + k_acon). 4 rows/wave,
// 16 rows/block; j-range staged in LDS in two halves (29.7 KB). Lane t holds
// row word t in a register -> one contiguous 456 B store per row, and the
// con-gather consumes the SAME register layout (no adj re-read).
//
// Exact division-free IoU test:
//   round_f32(inter/denom) >= 0.4f  <=>  inter > (0.4f - 2^-26)*denom in f64
//   (26x24-bit mantissa product is exact; midpoint ties round-to-even to
//   prev(0.4f) < 0.4f -> false, matching strict '>'). denom==0 => inter==0
//   => false, matching 0/0=NaN >= 0.4 false. Zero-padded boxes => false.
// thr[i][c] = max(adj_con, con_i): exact since p>=a && p>=b <=> p>=fmax(a,b)
// for non-NaN inputs; adj_con init 0 matches where(adj, con, 0).
// ---------------------------------------------------------------------------
__global__ __launch_bounds__(256, 4) void k_adjcon(const float* __restrict__ boxes,
                                                   const float* __restrict__ con,
                                                   u64* __restrict__ adj,
                                                   float* __restrict__ thr) {
#pragma clang fp contract(off)
    __shared__ float4 sbox[HW0_];    // (x1,y1,x2,y2), one j-half at a time
    const int tid  = threadIdx.x;
    const int lane = tid & 63;
    const int wv   = tid >> 6;
    const int g    = blockIdx.x;                 // 0 .. B*N/16-1
    const int b    = g / (N_ / RPB_);
    const int r0   = (g % (N_ / RPB_)) * RPB_ + wv * RPW_;
    const size_t bN = (size_t)b * N_;

    float4 bi[RPW_];
    float  ai[RPW_];
#pragma unroll
    for (int r = 0; r < RPW_; ++r) {
        const float4 bx = reinterpret_cast<const float4*>(boxes)[bN + r0 + r];
        const float x1 = bx.x - bx.z * 0.5f;   // cx - w/2 (reference op order)
        const float y1 = bx.y - bx.w * 0.5f;
        const float x2 = x1 + bx.z;
        const float y2 = y1 + bx.w;
        bi[r] = make_float4(x1, y1, x2, y2);
        ai[r] = (x2 - x1) * (y2 - y1);
    }
    const double MID = (double)0.4f - 0x1p-26;   // exact

    u64 row[RPW_];
#pragma unroll
    for (int r = 0; r < RPW_; ++r) row[r] = 0ull;

    int jbase = 0;
    for (int h = 0; h < 2; ++h) {
        const int cnt = h ? HW1_ : HW0_;
        __syncthreads();                         // protect previous half's reads
        for (int jj = tid; jj < cnt; jj += 256) {
            const int j = jbase + jj;
            float x1 = 0.f, y1 = 0.f, x2 = 0.f, y2 = 0.f;
            if (j < N_) {
                const float4 bx = reinterpret_cast<const float4*>(boxes)[bN + j];
                x1 = bx.x - bx.z * 0.5f;
                y1 = bx.y - bx.w * 0.5f;
                x2 = x1 + bx.z;
                y2 = y1 + bx.w;
            }
            sbox[jj] = make_float4(x1, y1, x2, y2);
        }
        __syncthreads();

        const int twn = cnt >> 6;
        for (int tw = 0; tw < twn; ++tw) {
            const int tglob = (jbase >> 6) + tw;
            const int j     = jbase + tw * 64 + lane;
            const float4 bj = sbox[tw * 64 + lane];
            const float ajr = (bj.z - bj.x) * (bj.w - bj.y);
#pragma unroll
            for (int r = 0; r < RPW_; ++r) {
                const float ltx = fmaxf(bi[r].x, bj.x);
                const float lty = fmaxf(bi[r].y, bj.y);
                const float rbx = fminf(bi[r].z, bj.z);
                const float rby = fminf(bi[r].w, bj.w);
                const float whx = fmaxf(rbx - ltx, 0.0f);
                const float why = fmaxf(rby - lty, 0.0f);
                const float inter = whx * why;
                const float denom = (ai[r] + ajr) - inter;
                const int pred = ((double)inter > MID * (double)denom) && (j != r0 + r);
                const u64 m = __ballot(pred);
                if (lane == tglob) row[r] = m;   // 2x v_cndmask
            }
        }
        jbase += cnt;
    }

    // store rows + fused sparse con-gather (register-resident row layout)
#pragma unroll
    for (int r = 0; r < RPW_; ++r) {
        const int i = r0 + r;
        if (lane < NW_) adj[(bN + i) * (size_t)NW_ + lane] = row[r];

        u64 w = row[r];                          // lanes >= NW_ hold 0
        float cm[C_];
#pragma unroll
        for (int k = 0; k < C_; ++k) cm[k] = 0.0f;
        while (w) {
            const int bit = __builtin_ctzll(w); w &= w - 1;
            const int j   = lane * 64 + bit;
            const float4* cp = reinterpret_cast<const float4*>(con + (bN + j) * C_);
            const float4 c0 = cp[0], c1 = cp[1], c2 = cp[2], c3 = cp[3];
            cm[0]  = fmaxf(cm[0],  c0.x); cm[1]  = fmaxf(cm[1],  c0.y);
            cm[2]  = fmaxf(cm[2],  c0.z); cm[3]  = fmaxf(cm[3],  c0.w);
            cm[4]  = fmaxf(cm[4],  c1.x); cm[5]  = fmaxf(cm[5],  c1.y);
            cm[6]  = fmaxf(cm[6],  c1.z); cm[7]  = fmaxf(cm[7],  c1.w);
            cm[8]  = fmaxf(cm[8],  c2.x); cm[9]  = fmaxf(cm[9],  c2.y);
            cm[10] = fmaxf(cm[10], c2.z); cm[11] = fmaxf(cm[11], c2.w);
            cm[12] = fmaxf(cm[12], c3.x); cm[13] = fmaxf(cm[13], c3.y);
            cm[14] = fmaxf(cm[14], c3.z); cm[15] = fmaxf(cm[15], c3.w);
        }
#pragma unroll
        for (int off = 1; off < 64; off <<= 1) {
#pragma unroll
            for (int k = 0; k < C_; ++k)
                cm[k] = fmaxf(cm[k], __shfl_xor(cm[k], off));
        }
        if (lane == 0) {
            const float4* cp = reinterpret_cast<const float4*>(con + (bN + i) * C_);
            const float4 c0 = cp[0], c1 = cp[1], c2 = cp[2], c3 = cp[3];
            float4* o = reinterpret_cast<float4*>(thr + (bN + i) * C_);
            o[0] = make_float4(fmaxf(cm[0],  c0.x), fmaxf(cm[1],  c0.y),
                               fmaxf(cm[2],  c0.z), fmaxf(cm[3],  c0.w));
            o[1] = make_float4(fmaxf(cm[4],  c1.x), fmaxf(cm[5],  c1.y),
                               fmaxf(cm[6],  c1.z), fmaxf(cm[7],  c1.w));
            o[2] = make_float4(fmaxf(cm[8],  c2.x), fmaxf(cm[9],  c2.y),
                               fmaxf(cm[10], c2.z), fmaxf(cm[11], c2.w));
            o[3] = make_float4(fmaxf(cm[12], c3.x), fmaxf(cm[13], c3.y),
                               fmaxf(cm[14], c3.z), fmaxf(cm[15], c3.w));
        }
    }
}

// ---------------------------------------------------------------------------
// K2: coalesced valid0 + global compaction. One thread per box, all 16 c.
// Nondeterministic compaction order is erased by k_sort (total-order keys).
// ---------------------------------------------------------------------------
__global__ __launch_bounds__(256) void k_valid(const float* __restrict__ pro,
                                               const float* __restrict__ thr,
                                               const float* __restrict__ conf,
                                               u64* __restrict__ keys_ws,
                                               u64* __restrict__ pvm_ws,
                                               u32* __restrict__ tcnt) {
    const int lane = threadIdx.x & 63;
    const int wv   = threadIdx.x >> 6;
    const int b    = blockIdx.x / NBLK_;
    const int blk  = blockIdx.x % NBLK_;
    const int i    = blk * 256 + wv * 64 + lane;
    const size_t bN = (size_t)b * N_;
    const int inb  = (i < N_);
    const int word = blk * 4 + wv;               // 0..59; words >=57 unused

    float pv[C_], tv[C_];
    if (inb) {
        const float4* pp = reinterpret_cast<const float4*>(pro + (bN + i) * C_);
        const float4* tp = reinterpret_cast<const float4*>(thr + (bN + i) * C_);
#pragma unroll
        for (int k = 0; k < 4; ++k) {
            const float4 a = pp[k];
            pv[4*k] = a.x; pv[4*k+1] = a.y; pv[4*k+2] = a.z; pv[4*k+3] = a.w;
            const float4 t = tp[k];
            tv[4*k] = t.x; tv[4*k+1] = t.y; tv[4*k+2] = t.z; tv[4*k+3] = t.w;
        }
    } else {
#pragma unroll
        for (int k = 0; k < C_; ++k) { pv[k] = 0.f; tv[k] = 0.f; }
    }

#pragma unroll
    for (int c = 0; c < C_; ++c) {
        const float cf = conf[c];
        const int pred = inb && (pv[c] >= cf) && (pv[c] >= tv[c]);
        const u64 bm = __ballot(pred);
        const size_t bc = (size_t)b * C_ + c;
        if (lane == 0) pvm_ws[bc * 64 + word] = bm;
        u32 base = 0;
        if (lane == 0 && bm) base = atomicAdd(&tcnt[bc], (u32)__popcll(bm));
        base = (u32)__shfl((int)base, 0);
        if (pred) {
            const u32 pb_ = __float_as_uint(pv[c]);
            const u32 pk  = pb_ ^ ((pb_ >> 31) ? 0xFFFFFFFFu : 0x80000000u);
            keys_ws[bc * N_ + base + (u32)__popcll(bm & ((1ull << lane) - 1ull))]
                = (((u64)(~pk)) << 32) | (u32)i;
        }
    }
}

// ---------------------------------------------------------------------------
// K3: per-(b,c) sort with hybrid segmented bitonic. Stage 1: each wave sorts
// its own 512-element LDS segments with wave-local passes (same-wave LDS is
// program-ordered; wave_barrier pins the compiler) — no block barriers.
// Stage 2: cross-segment merge passes use __syncthreads only while j>=512;
// j<512 passes are segment-local again (fixed wave<->segment mapping).
// Result ascending => score desc, idx asc (stable == argsort(-scores)).
// sidx_ws aliases keys_ws in global memory (keys fully staged to LDS first).
// ---------------------------------------------------------------------------
__global__ __launch_bounds__(256) void k_sort(const u64* __restrict__ keys_ws,
                                              const u32* __restrict__ tcnt,
                                              u32* __restrict__ sidx_ws) {
    __shared__ u64 keys[4096];
    const int tid  = threadIdx.x;
    const int lane = tid & 63;
    const int wv   = tid >> 6;
    const int bc   = blockIdx.x;

    const int T = (int)tcnt[bc];
    int P = 512;
    while (P < T) P <<= 1;                       // 512 <= P <= 4096
    for (int x = tid; x < P; x += 256)
        keys[x] = (x < T) ? keys_ws[(size_t)bc * N_ + x] : ~0ull;
    __syncthreads();

    const int nseg = P >> 9;
    // stage 1: wave-local 512 sorts (k = 2..512)
    for (int k = 2; k <= 512; k <<= 1) {
        for (int j = k >> 1; j > 0; j >>= 1) {
            for (int s = wv; s < nseg; s += 4) {
                const int base = s << 9;
                for (int t0 = lane; t0 < 512; t0 += 64) {
                    const int t = base + t0;
                    const int ixj = t ^ j;       // stays within the segment
                    if (ixj > t) {
                        const u64 a = keys[t], bb = keys[ixj];
                        const bool up = ((t & k) == 0);
                        if ((a > bb) == up) { keys[t] = bb; keys[ixj] = a; }
                    }
                }
            }
            __builtin_amdgcn_wave_barrier();
        }
    }
    __syncthreads();

    // stage 2: merges k = 1024..P
    for (int k = 1024; k <= P; k <<= 1) {
        for (int j = k >> 1; j >= 512; j >>= 1) {          // cross-segment
            for (int t = tid; t < P; t += 256) {
                const int ixj = t ^ j;
                if (ixj > t) {
                    const u64 a = keys[t], bb = keys[ixj];
                    const bool up = ((t & k) == 0);
                    if ((a > bb) == up) { keys[t] = bb; keys[ixj] = a; }
                }
            }
            __syncthreads();
        }
        for (int j = 256; j > 0; j >>= 1) {                // segment-local
            for (int s = wv; s < nseg; s += 4) {
                const int base = s << 9;
                for (int t0 = lane; t0 < 512; t0 += 64) {
                    const int t = base + t0;
                    const int ixj = t ^ j;
                    if (ixj > t) {
                        const u64 a = keys[t], bb = keys[ixj];
                        const bool up = ((t & k) == 0);
                        if ((a > bb) == up) { keys[t] = bb; keys[ixj] = a; }
                    }
                }
            }
            __builtin_amdgcn_wave_barrier();
        }
        __syncthreads();
    }

    for (int x = tid; x < T; x += 256)
        sidx_ws[(size_t)bc * N_ + x] = (u32)(keys[x] & 0xFFFFFFFFull);
}

// ---------------------------------------------------------------------------
// K4: chunk-parallel greedy NMS + output (round-8 proven kernel, verbatim).
// Valid bitmask lives in LDS. Per 64-candidate chunk: A) intra-chunk masks
// via adjacency symmetry + double-buffered row prefetch; B) wave-0 sparse
// resolve (steps == accepted count); C) parallel apply via atomicAnd.
// Exactness: candidate accepted iff valid at its turn under prior chunks'
// suppressions (vmask) and earlier accepted rows in-chunk (intra) — the
// reference greedy restricted to valid0 members (non-members never act since
// valid only shrinks). Survivors in greedy order == reference output order.
// ---------------------------------------------------------------------------
__global__ __launch_bounds__(256) void k_greedy(const u32* __restrict__ sidx_ws,
                                                const u64* __restrict__ pvm_ws,
                                                const u32* __restrict__ tcnt,
                                                const u64* __restrict__ adj,
                                                const float* __restrict__ pro,
                                                const float* __restrict__ boxes,
                                                const float* __restrict__ scales,
                                                float* __restrict__ out) {
#pragma clang fp contract(off)
    __shared__ u32 sidx[NPAD_];
    __shared__ u64 srows[2][CH_][NW_];
    __shared__ u64 sintra[CH_];
    __shared__ u64 vmask[NW_];
    __shared__ u64 s_accept;
    __shared__ u32 slist[NPAD_];
    __shared__ u32 s_S;
    const int tid  = threadIdx.x;
    const int lane = tid & 63;
    const int wv   = tid >> 6;
    const int bc   = blockIdx.x;
    const int b    = bc / C_, c = bc % C_;
    const size_t bN = (size_t)b * N_;

    const int T = (int)tcnt[bc];
    for (int x = tid; x < T; x += 256) sidx[x] = sidx_ws[(size_t)bc * N_ + x];
    if (tid < NW_) vmask[tid] = pvm_ws[(size_t)bc * 64 + tid];
    __syncthreads();

    // stage chunk 0
#pragma unroll
    for (int rr = 0; rr < 16; ++rr) {
        const int r = wv * 16 + rr;
        const u32 idx = (r < T) ? sidx[r] : 0u;
        if (lane < NW_) srows[0][r][lane] = adj[(bN + idx) * (size_t)NW_ + lane];
    }
    __syncthreads();

    u32 S = 0;                           // meaningful in wave 0
    const int NCH = (T + CH_ - 1) / CH_;
    for (int ch = 0; ch < NCH; ++ch) {
        const int cur = ch & 1, nxt = cur ^ 1;
        const int c0 = ch * CH_;
        const int cn = min(CH_, T - c0);
        const int havenext = (ch + 1 < NCH);

        // --- phase A: prefetch next chunk rows + intra-chunk masks ---
        u64 pre[16];
#pragma unroll
        for (int rr = 0; rr < 16; ++rr) {
            const int r = wv * 16 + rr;
            const int q = c0 + CH_ + r;
            const u32 idxn = (havenext && q < T) ? sidx[q] : 0u;
            pre[rr] = (havenext && lane < NW_)
                        ? adj[(bN + idxn) * (size_t)NW_ + lane] : 0ull;
        }
#pragma unroll
        for (int rr = 0; rr < 16; ++rr) {
            const int r = wv * 16 + rr;
            const u32 idxr = (c0 + r < T) ? sidx[c0 + r] : 0u;   // uniform/iter
            const u64 rj = srows[cur][lane][idxr >> 6];  // own row, sym. trick
            const u64 ib = __ballot((lane < cn) && ((rj >> (idxr & 63)) & 1ull));
            if (lane == 0) sintra[r] = ib;
        }
        __syncthreads();

        // --- phase B: wave 0 sparse resolve + survivor emit ---
        if (wv == 0) {
            const u32 idxme = (c0 + lane < T) ? sidx[c0 + lane] : 0u;
            const u64 vm = vmask[idxme >> 6];            // LDS scatter read
            u64 cv = __ballot((lane < cn) && ((vm >> (idxme & 63)) & 1ull));
            const u64 iv = sintra[lane];
            const u32 ivLo = (u32)iv, ivHi = (u32)(iv >> 32);
            u64 accept = 0ull;
            while (cv) {
                const int r = __builtin_ctzll(cv);
                accept |= 1ull << r;
                const u64 ir =
                    ((u64)(u32)__builtin_amdgcn_readlane((int)ivHi, r) << 32)
                  |  (u64)(u32)__builtin_amdgcn_readlane((int)ivLo, r);
                cv &= ~(ir | (1ull << r));
            }
            if (lane == 0) s_accept = accept;
            const u32 bitl = (u32)((accept >> lane) & 1ull);
            if (bitl) {
                const u32 pos = S + (u32)__popcll(accept & ((1ull << lane) - 1ull));
                slist[pos] = idxme;
            }
            S += (u32)__popcll(accept);
        }
        __syncthreads();

        // --- phase C: parallel apply + store prefetched rows ---
        const u64 ac = s_accept;
        u64 acc = 0ull;
#pragma unroll
        for (int rr = 0; rr < 16; ++rr) {
            const int r = wv * 16 + rr;
            if ((ac >> r) & 1ull)                        // wave-uniform branch
                acc |= srows[cur][r][min(lane, NW_ - 1)];
        }
        if (lane < NW_ && acc)
            atomicAnd(&vmask[lane], ~acc);
        if (havenext) {
#pragma unroll
            for (int rr = 0; rr < 16; ++rr) {
                const int r = wv * 16 + rr;
                if (lane < NW_) srows[nxt][r][lane] = pre[rr];
            }
        }
        __syncthreads();
    }
    if (wv == 0 && lane == 0) s_S = S;
    __syncthreads();

    // output survivors in greedy order (suppressed rows stay exact zeros)
    const int Sf = (int)s_S;
    const float s = scales[b];
    for (int r = tid; r < Sf; r += 256) {
        const int idx = (int)slist[r];
        const float4 bx = reinterpret_cast<const float4*>(boxes)[bN + idx];
        const float scx = bx.x * s, scy = bx.y * s, sw = bx.z * s, sh = bx.w * s;
        float* o = out + ((size_t)bc * N_ + r) * 5;
        o[0] = scx - 0.5f * sw;
        o[1] = scy - 0.5f * sh;
        o[2] = scx + 0.5f * sw;
        o[3] = scy + 0.5f * sh;
        o[4] = pro[(bN + idx) * C_ + c];
        out[(size_t)B_ * C_ * N_ * 5 + (size_t)bc * N_ + r] = 1.0f;
    }
}

// ---------------------------------------------------------------------------
extern "C" void kernel_launch(void* const* d_in, const int* in_sizes, int n_in,
                              void* d_out, int out_size, void* d_ws, size_t ws_size,
                              hipStream_t stream) {
    const float* pro    = (const float*)d_in[0];   // (B,N,C)
    const float* con    = (const float*)d_in[1];   // (B,N,C)
    const float* boxes  = (const float*)d_in[2];   // (B,N,4)
    const float* scales = (const float*)d_in[3];   // (B,)
    const float* conf   = (const float*)d_in[4];   // (C,)

    char* ws = (char*)d_ws;
    u64* adj = (u64*)ws;                                   // B*N*NW u64  (6.57 MB)
    size_t off = (size_t)B_ * N_ * NW_ * sizeof(u64);
    float* thr = (float*)(ws + off);                       // B*N*C f32   (0.92 MB)
    off += (size_t)B_ * N_ * C_ * sizeof(float);
    u64* keys_ws = (u64*)(ws + off);                       // B*C*N u64   (1.84 MB)
    u32* sidx_ws = (u32*)keys_ws;                          // aliases keys (safe:
                                                           // k_sort stages keys to
                                                           // LDS before writing)
    off += (size_t)B_ * C_ * N_ * sizeof(u64);
    u64* pvm_ws = (u64*)(ws + off);                        // 64*64 u64   (32 KB)
    off += (size_t)B_ * C_ * 64 * sizeof(u64);
    u32* tcnt = (u32*)(ws + off);                          // 64 u32

    hipMemsetAsync(d_out, 0, (size_t)out_size * sizeof(float), stream);
    hipMemsetAsync(tcnt, 0, B_ * C_ * sizeof(u32), stream);
    k_adjcon<<<B_ * N_ / RPB_, 256, 0, stream>>>(boxes, con, adj, thr);
    k_valid <<<B_ * NBLK_,     256, 0, stream>>>(pro, thr, conf, keys_ws, pvm_ws, tcnt);
    k_sort  <<<B_ * C_,        256, 0, stream>>>(keys_ws, tcnt, sidx_ws);
    k_greedy<<<B_ * C_,        256, 0, stream>>>(sidx_ws, pvm_ws, tcnt, adj, pro,
                                                 boxes, scales, (float*)d_out);
}

// Round 12
// 231.950 us; speedup vs baseline: 1.0339x; 1.0339x over previous
//
#include <hip/hip_runtime.h>
#include <cstdint>

typedef unsigned long long u64;
typedef unsigned int u32;

#define B_ 4
#define N_ 3600
#define C_ 16
#define NW_ 57        // ceil(N/64) words of adjacency/valid bitmask
#define NPAD_ 3648    // NW_*64
#define RPW_ 4        // rows per wave (k_adjcon)
#define RPB_ 16       // rows per block (k_adjcon, 4 waves)
#define HW0_ 1856     // j-half 0: words 0..28  (29 words)
#define HW1_ 1792     // j-half 1: words 29..56 (28 words)
#define CH_ 64        // greedy chunk size

// ---------------------------------------------------------------------------
// K1: adjacency bitmask + fused threshold (measured 68 us, r11). 4 rows/wave,
// 16 rows/block; j-range staged in LDS in two halves (29.7 KB). Lane t holds
// row word t in a register -> one contiguous 456 B store per row, and the
// con-gather consumes the SAME register layout (no adj re-read).
//
// Exact division-free IoU test:
//   round_f32(inter/denom) >= 0.4f  <=>  inter > (0.4f - 2^-26)*denom in f64
//   (26x24-bit mantissa product is exact; midpoint ties round-to-even to
//   prev(0.4f) < 0.4f -> false, matching strict '>'). denom==0 => inter==0
//   => false, matching 0/0=NaN >= 0.4 false. Zero-padded boxes => false.
// thr[i][c] = max(adj_con, con_i): exact since p>=a && p>=b <=> p>=fmax(a,b)
// for non-NaN inputs; adj_con init 0 matches where(adj, con, 0).
// ---------------------------------------------------------------------------
__global__ __launch_bounds__(256, 4) void k_adjcon(const float* __restrict__ boxes,
                                                   const float* __restrict__ con,
                                                   u64* __restrict__ adj,
                                                   float* __restrict__ thr) {
#pragma clang fp contract(off)
    __shared__ float4 sbox[HW0_];    // (x1,y1,x2,y2), one j-half at a time
    const int tid  = threadIdx.x;
    const int lane = tid & 63;
    const int wv   = tid >> 6;
    const int g    = blockIdx.x;                 // 0 .. B*N/16-1
    const int b    = g / (N_ / RPB_);
    const int r0   = (g % (N_ / RPB_)) * RPB_ + wv * RPW_;
    const size_t bN = (size_t)b * N_;

    float4 bi[RPW_];
    float  ai[RPW_];
#pragma unroll
    for (int r = 0; r < RPW_; ++r) {
        const float4 bx = reinterpret_cast<const float4*>(boxes)[bN + r0 + r];
        const float x1 = bx.x - bx.z * 0.5f;   // cx - w/2 (reference op order)
        const float y1 = bx.y - bx.w * 0.5f;
        const float x2 = x1 + bx.z;
        const float y2 = y1 + bx.w;
        bi[r] = make_float4(x1, y1, x2, y2);
        ai[r] = (x2 - x1) * (y2 - y1);
    }
    const double MID = (double)0.4f - 0x1p-26;   // exact

    u64 row[RPW_];
#pragma unroll
    for (int r = 0; r < RPW_; ++r) row[r] = 0ull;

    int jbase = 0;
    for (int h = 0; h < 2; ++h) {
        const int cnt = h ? HW1_ : HW0_;
        __syncthreads();                         // protect previous half's reads
        for (int jj = tid; jj < cnt; jj += 256) {
            const int j = jbase + jj;
            float x1 = 0.f, y1 = 0.f, x2 = 0.f, y2 = 0.f;
            if (j < N_) {
                const float4 bx = reinterpret_cast<const float4*>(boxes)[bN + j];
                x1 = bx.x - bx.z * 0.5f;
                y1 = bx.y - bx.w * 0.5f;
                x2 = x1 + bx.z;
                y2 = y1 + bx.w;
            }
            sbox[jj] = make_float4(x1, y1, x2, y2);
        }
        __syncthreads();

        const int twn = cnt >> 6;
        for (int tw = 0; tw < twn; ++tw) {
            const int tglob = (jbase >> 6) + tw;
            const int j     = jbase + tw * 64 + lane;
            const float4 bj = sbox[tw * 64 + lane];
            const float ajr = (bj.z - bj.x) * (bj.w - bj.y);
#pragma unroll
            for (int r = 0; r < RPW_; ++r) {
                const float ltx = fmaxf(bi[r].x, bj.x);
                const float lty = fmaxf(bi[r].y, bj.y);
                const float rbx = fminf(bi[r].z, bj.z);
                const float rby = fminf(bi[r].w, bj.w);
                const float whx = fmaxf(rbx - ltx, 0.0f);
                const float why = fmaxf(rby - lty, 0.0f);
                const float inter = whx * why;
                const float denom = (ai[r] + ajr) - inter;
                const int pred = ((double)inter > MID * (double)denom) && (j != r0 + r);
                const u64 m = __ballot(pred);
                if (lane == tglob) row[r] = m;   // 2x v_cndmask
            }
        }
        jbase += cnt;
    }

    // store rows + fused sparse con-gather (register-resident row layout)
#pragma unroll
    for (int r = 0; r < RPW_; ++r) {
        const int i = r0 + r;
        if (lane < NW_) adj[(bN + i) * (size_t)NW_ + lane] = row[r];

        u64 w = row[r];                          // lanes >= NW_ hold 0
        float cm[C_];
#pragma unroll
        for (int k = 0; k < C_; ++k) cm[k] = 0.0f;
        while (w) {
            const int bit = __builtin_ctzll(w); w &= w - 1;
            const int j   = lane * 64 + bit;
            const float4* cp = reinterpret_cast<const float4*>(con + (bN + j) * C_);
            const float4 c0 = cp[0], c1 = cp[1], c2 = cp[2], c3 = cp[3];
            cm[0]  = fmaxf(cm[0],  c0.x); cm[1]  = fmaxf(cm[1],  c0.y);
            cm[2]  = fmaxf(cm[2],  c0.z); cm[3]  = fmaxf(cm[3],  c0.w);
            cm[4]  = fmaxf(cm[4],  c1.x); cm[5]  = fmaxf(cm[5],  c1.y);
            cm[6]  = fmaxf(cm[6],  c1.z); cm[7]  = fmaxf(cm[7],  c1.w);
            cm[8]  = fmaxf(cm[8],  c2.x); cm[9]  = fmaxf(cm[9],  c2.y);
            cm[10] = fmaxf(cm[10], c2.z); cm[11] = fmaxf(cm[11], c2.w);
            cm[12] = fmaxf(cm[12], c3.x); cm[13] = fmaxf(cm[13], c3.y);
            cm[14] = fmaxf(cm[14], c3.z); cm[15] = fmaxf(cm[15], c3.w);
        }
#pragma unroll
        for (int off = 1; off < 64; off <<= 1) {
#pragma unroll
            for (int k = 0; k < C_; ++k)
                cm[k] = fmaxf(cm[k], __shfl_xor(cm[k], off));
        }
        if (lane == 0) {
            const float4* cp = reinterpret_cast<const float4*>(con + (bN + i) * C_);
            const float4 c0 = cp[0], c1 = cp[1], c2 = cp[2], c3 = cp[3];
            float4* o = reinterpret_cast<float4*>(thr + (bN + i) * C_);
            o[0] = make_float4(fmaxf(cm[0],  c0.x), fmaxf(cm[1],  c0.y),
                               fmaxf(cm[2],  c0.z), fmaxf(cm[3],  c0.w));
            o[1] = make_float4(fmaxf(cm[4],  c1.x), fmaxf(cm[5],  c1.y),
                               fmaxf(cm[6],  c1.z), fmaxf(cm[7],  c1.w));
            o[2] = make_float4(fmaxf(cm[8],  c2.x), fmaxf(cm[9],  c2.y),
                               fmaxf(cm[10], c2.z), fmaxf(cm[11], c2.w));
            o[3] = make_float4(fmaxf(cm[12], c3.x), fmaxf(cm[13], c3.y),
                               fmaxf(cm[14], c3.z), fmaxf(cm[15], c3.w));
        }
    }
}

// ---------------------------------------------------------------------------
// K2: valid0 + compaction + hybrid segmented bitonic sort per (b,c) (r8's
// proven k_prep, sort upgraded to the r11-verified low-barrier hybrid).
// Writes sorted candidate indices (score desc, idx asc — stable ==
// argsort(-scores)), valid0 ballots, and the count (no tcnt memset needed).
// ---------------------------------------------------------------------------
__global__ __launch_bounds__(256) void k_prep(const float* __restrict__ pro,
                                              const float* __restrict__ thr,
                                              const float* __restrict__ conf,
                                              u32* __restrict__ sidx_ws,
                                              u64* __restrict__ pvm_ws,
                                              u32* __restrict__ tcnt) {
    __shared__ u64 keys[4096];           // (~score_bits << 32) | idx (asc sort)
    __shared__ u32 s_T;
    const int tid  = threadIdx.x;
    const int lane = tid & 63;
    const int wv   = tid >> 6;
    const int bc   = blockIdx.x;
    const int b    = bc / C_, c = bc % C_;
    const size_t bN = (size_t)b * N_;
    const float cf = conf[c];

    if (tid == 0) s_T = 0;
    __syncthreads();

    // --- valid0 + unordered keyed compaction ---
    for (int t = wv; t < NW_; t += 4) {
        const int i = t * 64 + lane;
        int pred = 0;
        u32 pk = 0;
        if (i < N_) {
            const size_t off = (bN + i) * C_ + c;
            const float p = pro[off];
            pred = (p >= cf) && (p >= thr[off]);
            const u32 pb = __float_as_uint(p);
            pk = pb ^ ((pb >> 31) ? 0xFFFFFFFFu : 0x80000000u);
        }
        const u64 bm = __ballot(pred);
        if (lane == 0) pvm_ws[(size_t)bc * 64 + t] = bm;
        u32 base = 0;
        if (lane == 0 && bm) base = atomicAdd(&s_T, (u32)__popcll(bm));
        base = (u32)__shfl((int)base, 0);
        if (pred) keys[base + (u32)__popcll(bm & ((1ull << lane) - 1ull))] =
            (((u64)(~pk)) << 32) | (u32)i;
    }
    __syncthreads();

    const int T = (int)s_T;
    int P = 512;
    while (P < T) P <<= 1;               // 512 <= P <= 4096
    for (int x = T + tid; x < P; x += 256) keys[x] = ~0ull;
    __syncthreads();

    // --- hybrid segmented bitonic sort (asc => score desc, idx asc) ---
    const int nseg = P >> 9;
    // stage 1: wave-local 512 sorts (k = 2..512); same-wave LDS is
    // program-ordered, wave_barrier pins pass boundaries.
    for (int k = 2; k <= 512; k <<= 1) {
        for (int j = k >> 1; j > 0; j >>= 1) {
            for (int s = wv; s < nseg; s += 4) {
                const int base = s << 9;
                for (int t0 = lane; t0 < 512; t0 += 64) {
                    const int t = base + t0;
                    const int ixj = t ^ j;       // stays within the segment
                    if (ixj > t) {
                        const u64 a = keys[t], bb = keys[ixj];
                        const bool up = ((t & k) == 0);
                        if ((a > bb) == up) { keys[t] = bb; keys[ixj] = a; }
                    }
                }
            }
            __builtin_amdgcn_wave_barrier();
        }
    }
    __syncthreads();
    // stage 2: merges k = 1024..P
    for (int k = 1024; k <= P; k <<= 1) {
        for (int j = k >> 1; j >= 512; j >>= 1) {          // cross-segment
            for (int t = tid; t < P; t += 256) {
                const int ixj = t ^ j;
                if (ixj > t) {
                    const u64 a = keys[t], bb = keys[ixj];
                    const bool up = ((t & k) == 0);
                    if ((a > bb) == up) { keys[t] = bb; keys[ixj] = a; }
                }
            }
            __syncthreads();
        }
        for (int j = 256; j > 0; j >>= 1) {                // segment-local
            for (int s = wv; s < nseg; s += 4) {
                const int base = s << 9;
                for (int t0 = lane; t0 < 512; t0 += 64) {
                    const int t = base + t0;
                    const int ixj = t ^ j;
                    if (ixj > t) {
                        const u64 a = keys[t], bb = keys[ixj];
                        const bool up = ((t & k) == 0);
                        if ((a > bb) == up) { keys[t] = bb; keys[ixj] = a; }
                    }
                }
            }
            __builtin_amdgcn_wave_barrier();
        }
        __syncthreads();
    }

    for (int x = tid; x < T; x += 256)
        sidx_ws[(size_t)bc * N_ + x] = (u32)(keys[x] & 0xFFFFFFFFull);
    if (tid == 0) tcnt[bc] = (u32)T;
}

// ---------------------------------------------------------------------------
// K3: chunk-parallel greedy NMS + output (round-8 proven kernel, verbatim;
// measured 52 us). Valid bitmask lives in LDS. Per 64-candidate chunk:
// A) intra-chunk masks via adjacency symmetry + double-buffered row prefetch;
// B) wave-0 sparse resolve (steps == accepted count); C) parallel apply via
// atomicAnd. Exactness: candidate accepted iff valid at its turn under prior
// chunks' suppressions (vmask) and earlier accepted rows in-chunk (intra) —
// the reference greedy restricted to valid0 members (non-members never act
// since valid only shrinks). Survivors in greedy order == reference output
// order (suppressed rows exact zeros; stable ties).
// ---------------------------------------------------------------------------
__global__ __launch_bounds__(256) void k_greedy(const u32* __restrict__ sidx_ws,
                                                const u64* __restrict__ pvm_ws,
                                                const u32* __restrict__ tcnt,
                                                const u64* __restrict__ adj,
                                                const float* __restrict__ pro,
                                                const float* __restrict__ boxes,
                                                const float* __restrict__ scales,
                                                float* __restrict__ out) {
#pragma clang fp contract(off)
    __shared__ u32 sidx[NPAD_];
    __shared__ u64 srows[2][CH_][NW_];
    __shared__ u64 sintra[CH_];
    __shared__ u64 vmask[NW_];
    __shared__ u64 s_accept;
    __shared__ u32 slist[NPAD_];
    __shared__ u32 s_S;
    const int tid  = threadIdx.x;
    const int lane = tid & 63;
    const int wv   = tid >> 6;
    const int bc   = blockIdx.x;
    const int b    = bc / C_, c = bc % C_;
    const size_t bN = (size_t)b * N_;

    const int T = (int)tcnt[bc];
    for (int x = tid; x < T; x += 256) sidx[x] = sidx_ws[(size_t)bc * N_ + x];
    if (tid < NW_) vmask[tid] = pvm_ws[(size_t)bc * 64 + tid];
    __syncthreads();

    // stage chunk 0
#pragma unroll
    for (int rr = 0; rr < 16; ++rr) {
        const int r = wv * 16 + rr;
        const u32 idx = (r < T) ? sidx[r] : 0u;
        if (lane < NW_) srows[0][r][lane] = adj[(bN + idx) * (size_t)NW_ + lane];
    }
    __syncthreads();

    u32 S = 0;                           // meaningful in wave 0
    const int NCH = (T + CH_ - 1) / CH_;
    for (int ch = 0; ch < NCH; ++ch) {
        const int cur = ch & 1, nxt = cur ^ 1;
        const int c0 = ch * CH_;
        const int cn = min(CH_, T - c0);
        const int havenext = (ch + 1 < NCH);

        // --- phase A: prefetch next chunk rows + intra-chunk masks ---
        u64 pre[16];
#pragma unroll
        for (int rr = 0; rr < 16; ++rr) {
            const int r = wv * 16 + rr;
            const int q = c0 + CH_ + r;
            const u32 idxn = (havenext && q < T) ? sidx[q] : 0u;
            pre[rr] = (havenext && lane < NW_)
                        ? adj[(bN + idxn) * (size_t)NW_ + lane] : 0ull;
        }
#pragma unroll
        for (int rr = 0; rr < 16; ++rr) {
            const int r = wv * 16 + rr;
            const u32 idxr = (c0 + r < T) ? sidx[c0 + r] : 0u;   // uniform/iter
            const u64 rj = srows[cur][lane][idxr >> 6];  // own row, sym. trick
            const u64 ib = __ballot((lane < cn) && ((rj >> (idxr & 63)) & 1ull));
            if (lane == 0) sintra[r] = ib;
        }
        __syncthreads();

        // --- phase B: wave 0 sparse resolve + survivor emit ---
        if (wv == 0) {
            const u32 idxme = (c0 + lane < T) ? sidx[c0 + lane] : 0u;
            const u64 vm = vmask[idxme >> 6];            // LDS scatter read
            u64 cv = __ballot((lane < cn) && ((vm >> (idxme & 63)) & 1ull));
            const u64 iv = sintra[lane];
            const u32 ivLo = (u32)iv, ivHi = (u32)(iv >> 32);
            u64 accept = 0ull;
            while (cv) {
                const int r = __builtin_ctzll(cv);
                accept |= 1ull << r;
                const u64 ir =
                    ((u64)(u32)__builtin_amdgcn_readlane((int)ivHi, r) << 32)
                  |  (u64)(u32)__builtin_amdgcn_readlane((int)ivLo, r);
                cv &= ~(ir | (1ull << r));
            }
            if (lane == 0) s_accept = accept;
            const u32 bitl = (u32)((accept >> lane) & 1ull);
            if (bitl) {
                const u32 pos = S + (u32)__popcll(accept & ((1ull << lane) - 1ull));
                slist[pos] = idxme;
            }
            S += (u32)__popcll(accept);
        }
        __syncthreads();

        // --- phase C: parallel apply + store prefetched rows ---
        const u64 ac = s_accept;
        u64 acc = 0ull;
#pragma unroll
        for (int rr = 0; rr < 16; ++rr) {
            const int r = wv * 16 + rr;
            if ((ac >> r) & 1ull)                        // wave-uniform branch
                acc |= srows[cur][r][min(lane, NW_ - 1)];
        }
        if (lane < NW_ && acc)
            atomicAnd(&vmask[lane], ~acc);
        if (havenext) {
#pragma unroll
            for (int rr = 0; rr < 16; ++rr) {
                const int r = wv * 16 + rr;
                if (lane < NW_) srows[nxt][r][lane] = pre[rr];
            }
        }
        __syncthreads();
    }
    if (wv == 0 && lane == 0) s_S = S;
    __syncthreads();

    // output survivors in greedy order (suppressed rows stay exact zeros)
    const int Sf = (int)s_S;
    const float s = scales[b];
    for (int r = tid; r < Sf; r += 256) {
        const int idx = (int)slist[r];
        const float4 bx = reinterpret_cast<const float4*>(boxes)[bN + idx];
        const float scx = bx.x * s, scy = bx.y * s, sw = bx.z * s, sh = bx.w * s;
        float* o = out + ((size_t)bc * N_ + r) * 5;
        o[0] = scx - 0.5f * sw;
        o[1] = scy - 0.5f * sh;
        o[2] = scx + 0.5f * sw;
        o[3] = scy + 0.5f * sh;
        o[4] = pro[(bN + idx) * C_ + c];
        out[(size_t)B_ * C_ * N_ * 5 + (size_t)bc * N_ + r] = 1.0f;
    }
}

// ---------------------------------------------------------------------------
extern "C" void kernel_launch(void* const* d_in, const int* in_sizes, int n_in,
                              void* d_out, int out_size, void* d_ws, size_t ws_size,
                              hipStream_t stream) {
    const float* pro    = (const float*)d_in[0];   // (B,N,C)
    const float* con    = (const float*)d_in[1];   // (B,N,C)
    const float* boxes  = (const float*)d_in[2];   // (B,N,4)
    const float* scales = (const float*)d_in[3];   // (B,)
    const float* conf   = (const float*)d_in[4];   // (C,)

    char* ws = (char*)d_ws;
    u64* adj = (u64*)ws;                                   // B*N*NW u64  (6.57 MB)
    size_t off = (size_t)B_ * N_ * NW_ * sizeof(u64);
    float* thr = (float*)(ws + off);                       // B*N*C f32   (0.92 MB)
    off += (size_t)B_ * N_ * C_ * sizeof(float);
    u32* sidx_ws = (u32*)(ws + off);                       // B*C*N u32   (0.92 MB)
    off += (size_t)B_ * C_ * N_ * sizeof(u32);
    u64* pvm_ws = (u64*)(ws + off);                        // 64*64 u64   (32 KB)
    off += (size_t)B_ * C_ * 64 * sizeof(u64);
    u32* tcnt = (u32*)(ws + off);                          // 64 u32

    hipMemsetAsync(d_out, 0, (size_t)out_size * sizeof(float), stream);
    k_adjcon<<<B_ * N_ / RPB_, 256, 0, stream>>>(boxes, con, adj, thr);
    k_prep  <<<B_ * C_,        256, 0, stream>>>(pro, thr, conf, sidx_ws, pvm_ws, tcnt);
    k_greedy<<<B_ * C_,        256, 0, stream>>>(sidx_ws, pvm_ws, tcnt, adj, pro,
                                                 boxes, scales, (float*)d_out);
}

// Round 13
// 204.168 us; speedup vs baseline: 1.1746x; 1.1361x over previous
//
#include <hip/hip_runtime.h>
#include <cstdint>

typedef unsigned long long u64;
typedef unsigned int u32;

#define B_ 4
#define N_ 3600
#define C_ 16
#define NW_ 57        // ceil(N/64) words of adjacency/valid bitmask
#define NPAD_ 3648    // NW_*64
#define RPW_ 4        // rows per wave (k_adjcon)
#define RPB_ 16       // rows per block (k_adjcon, 4 waves)
#define HW0_ 1856     // j-half 0: words 0..28  (29 words)
#define HW1_ 1792     // j-half 1: words 29..56 (28 words)
#define CH_ 64        // greedy chunk size

// ---------------------------------------------------------------------------
// K1: adjacency bitmask + fused threshold (measured 68 us, r11/r12). 4 rows/
// wave, 16 rows/block; j-range staged in LDS in two halves (29.7 KB). Lane t
// holds row word t in a register -> one contiguous 456 B store per row, and
// the con-gather consumes the SAME register layout (no adj re-read).
//
// Exact division-free IoU test:
//   round_f32(inter/denom) >= 0.4f  <=>  inter > (0.4f - 2^-26)*denom in f64
//   (26x24-bit mantissa product is exact; midpoint ties round-to-even to
//   prev(0.4f) < 0.4f -> false, matching strict '>'). denom==0 => inter==0
//   => false, matching 0/0=NaN >= 0.4 false. Zero-padded boxes => false.
// thr[i][c] = max(adj_con, con_i): exact since p>=a && p>=b <=> p>=fmax(a,b)
// for non-NaN inputs; adj_con init 0 matches where(adj, con, 0).
// ---------------------------------------------------------------------------
__global__ __launch_bounds__(256, 4) void k_adjcon(const float* __restrict__ boxes,
                                                   const float* __restrict__ con,
                                                   u64* __restrict__ adj,
                                                   float* __restrict__ thr) {
#pragma clang fp contract(off)
    __shared__ float4 sbox[HW0_];    // (x1,y1,x2,y2), one j-half at a time
    const int tid  = threadIdx.x;
    const int lane = tid & 63;
    const int wv   = tid >> 6;
    const int g    = blockIdx.x;                 // 0 .. B*N/16-1
    const int b    = g / (N_ / RPB_);
    const int r0   = (g % (N_ / RPB_)) * RPB_ + wv * RPW_;
    const size_t bN = (size_t)b * N_;

    float4 bi[RPW_];
    float  ai[RPW_];
#pragma unroll
    for (int r = 0; r < RPW_; ++r) {
        const float4 bx = reinterpret_cast<const float4*>(boxes)[bN + r0 + r];
        const float x1 = bx.x - bx.z * 0.5f;   // cx - w/2 (reference op order)
        const float y1 = bx.y - bx.w * 0.5f;
        const float x2 = x1 + bx.z;
        const float y2 = y1 + bx.w;
        bi[r] = make_float4(x1, y1, x2, y2);
        ai[r] = (x2 - x1) * (y2 - y1);
    }
    const double MID = (double)0.4f - 0x1p-26;   // exact

    u64 row[RPW_];
#pragma unroll
    for (int r = 0; r < RPW_; ++r) row[r] = 0ull;

    int jbase = 0;
    for (int h = 0; h < 2; ++h) {
        const int cnt = h ? HW1_ : HW0_;
        __syncthreads();                         // protect previous half's reads
        for (int jj = tid; jj < cnt; jj += 256) {
            const int j = jbase + jj;
            float x1 = 0.f, y1 = 0.f, x2 = 0.f, y2 = 0.f;
            if (j < N_) {
                const float4 bx = reinterpret_cast<const float4*>(boxes)[bN + j];
                x1 = bx.x - bx.z * 0.5f;
                y1 = bx.y - bx.w * 0.5f;
                x2 = x1 + bx.z;
                y2 = y1 + bx.w;
            }
            sbox[jj] = make_float4(x1, y1, x2, y2);
        }
        __syncthreads();

        const int twn = cnt >> 6;
        for (int tw = 0; tw < twn; ++tw) {
            const int tglob = (jbase >> 6) + tw;
            const int j     = jbase + tw * 64 + lane;
            const float4 bj = sbox[tw * 64 + lane];
            const float ajr = (bj.z - bj.x) * (bj.w - bj.y);
#pragma unroll
            for (int r = 0; r < RPW_; ++r) {
                const float ltx = fmaxf(bi[r].x, bj.x);
                const float lty = fmaxf(bi[r].y, bj.y);
                const float rbx = fminf(bi[r].z, bj.z);
                const float rby = fminf(bi[r].w, bj.w);
                const float whx = fmaxf(rbx - ltx, 0.0f);
                const float why = fmaxf(rby - lty, 0.0f);
                const float inter = whx * why;
                const float denom = (ai[r] + ajr) - inter;
                const int pred = ((double)inter > MID * (double)denom) && (j != r0 + r);
                const u64 m = __ballot(pred);
                if (lane == tglob) row[r] = m;   // 2x v_cndmask
            }
        }
        jbase += cnt;
    }

    // store rows + fused sparse con-gather (register-resident row layout)
#pragma unroll
    for (int r = 0; r < RPW_; ++r) {
        const int i = r0 + r;
        if (lane < NW_) adj[(bN + i) * (size_t)NW_ + lane] = row[r];

        u64 w = row[r];                          // lanes >= NW_ hold 0
        float cm[C_];
#pragma unroll
        for (int k = 0; k < C_; ++k) cm[k] = 0.0f;
        while (w) {
            const int bit = __builtin_ctzll(w); w &= w - 1;
            const int j   = lane * 64 + bit;
            const float4* cp = reinterpret_cast<const float4*>(con + (bN + j) * C_);
            const float4 c0 = cp[0], c1 = cp[1], c2 = cp[2], c3 = cp[3];
            cm[0]  = fmaxf(cm[0],  c0.x); cm[1]  = fmaxf(cm[1],  c0.y);
            cm[2]  = fmaxf(cm[2],  c0.z); cm[3]  = fmaxf(cm[3],  c0.w);
            cm[4]  = fmaxf(cm[4],  c1.x); cm[5]  = fmaxf(cm[5],  c1.y);
            cm[6]  = fmaxf(cm[6],  c1.z); cm[7]  = fmaxf(cm[7],  c1.w);
            cm[8]  = fmaxf(cm[8],  c2.x); cm[9]  = fmaxf(cm[9],  c2.y);
            cm[10] = fmaxf(cm[10], c2.z); cm[11] = fmaxf(cm[11], c2.w);
            cm[12] = fmaxf(cm[12], c3.x); cm[13] = fmaxf(cm[13], c3.y);
            cm[14] = fmaxf(cm[14], c3.z); cm[15] = fmaxf(cm[15], c3.w);
        }
#pragma unroll
        for (int off = 1; off < 64; off <<= 1) {
#pragma unroll
            for (int k = 0; k < C_; ++k)
                cm[k] = fmaxf(cm[k], __shfl_xor(cm[k], off));
        }
        if (lane == 0) {
            const float4* cp = reinterpret_cast<const float4*>(con + (bN + i) * C_);
            const float4 c0 = cp[0], c1 = cp[1], c2 = cp[2], c3 = cp[3];
            float4* o = reinterpret_cast<float4*>(thr + (bN + i) * C_);
            o[0] = make_float4(fmaxf(cm[0],  c0.x), fmaxf(cm[1],  c0.y),
                               fmaxf(cm[2],  c0.z), fmaxf(cm[3],  c0.w));
            o[1] = make_float4(fmaxf(cm[4],  c1.x), fmaxf(cm[5],  c1.y),
                               fmaxf(cm[6],  c1.z), fmaxf(cm[7],  c1.w));
            o[2] = make_float4(fmaxf(cm[8],  c2.x), fmaxf(cm[9],  c2.y),
                               fmaxf(cm[10], c2.z), fmaxf(cm[11], c2.w));
            o[3] = make_float4(fmaxf(cm[12], c3.x), fmaxf(cm[13], c3.y),
                               fmaxf(cm[14], c3.z), fmaxf(cm[15], c3.w));
        }
    }
}

// ---------------------------------------------------------------------------
// K2: valid0 + compaction + PLAIN bitonic sort per (b,c) — round-8's exact
// kernel (measured ~27 us inside r8's 202.8 total; the r12 hybrid sort was
// ~60 us slower and is reverted). Writes sorted candidate indices (score
// desc, idx asc — stable == argsort(-scores)), valid0 ballots, and count.
// ---------------------------------------------------------------------------
__global__ __launch_bounds__(256) void k_prep(const float* __restrict__ pro,
                                              const float* __restrict__ thr,
                                              const float* __restrict__ conf,
                                              u32* __restrict__ sidx_ws,
                                              u64* __restrict__ pvm_ws,
                                              u32* __restrict__ tcnt) {
    __shared__ u64 keys[4096];           // (~score_bits << 32) | idx (asc sort)
    __shared__ u32 s_T;
    const int tid  = threadIdx.x;
    const int lane = tid & 63;
    const int wv   = tid >> 6;
    const int bc   = blockIdx.x;
    const int b    = bc / C_, c = bc % C_;
    const size_t bN = (size_t)b * N_;
    const float cf = conf[c];

    if (tid == 0) s_T = 0;
    __syncthreads();

    for (int t = wv; t < NW_; t += 4) {
        const int i = t * 64 + lane;
        int pred = 0;
        u32 pk = 0;
        if (i < N_) {
            const size_t off = (bN + i) * C_ + c;
            const float p = pro[off];
            pred = (p >= cf) && (p >= thr[off]);
            const u32 pb = __float_as_uint(p);
            pk = pb ^ ((pb >> 31) ? 0xFFFFFFFFu : 0x80000000u);
        }
        const u64 bm = __ballot(pred);
        if (lane == 0) pvm_ws[(size_t)bc * 64 + t] = bm;
        u32 base = 0;
        if (lane == 0 && bm) base = atomicAdd(&s_T, (u32)__popcll(bm));
        base = (u32)__shfl((int)base, 0);
        if (pred) keys[base + (u32)__popcll(bm & ((1ull << lane) - 1ull))] =
            (((u64)(~pk)) << 32) | (u32)i;
    }
    __syncthreads();

    const int T = (int)s_T;
    int P = 2;
    while (P < T) P <<= 1;               // P <= 4096
    for (int x = T + tid; x < P; x += 256) keys[x] = ~0ull;
    __syncthreads();

    for (int k = 2; k <= P; k <<= 1) {
        for (int j = k >> 1; j > 0; j >>= 1) {
            for (int t = tid; t < P; t += 256) {
                const int ixj = t ^ j;
                if (ixj > t) {
                    const u64 a = keys[t], bb = keys[ixj];
                    const bool up = ((t & k) == 0);
                    if ((a > bb) == up) { keys[t] = bb; keys[ixj] = a; }
                }
            }
            __syncthreads();
        }
    }

    for (int x = tid; x < T; x += 256)
        sidx_ws[(size_t)bc * N_ + x] = (u32)(keys[x] & 0xFFFFFFFFull);
    if (tid == 0) tcnt[bc] = (u32)T;
}

// ---------------------------------------------------------------------------
// K3: chunk-parallel greedy NMS + output (round-8 proven kernel, verbatim;
// measured 52 us). Valid bitmask lives in LDS. Per 64-candidate chunk:
// A) intra-chunk masks via adjacency symmetry + double-buffered row prefetch;
// B) wave-0 sparse resolve (steps == accepted count); C) parallel apply via
// atomicAnd. Exactness: candidate accepted iff valid at its turn under prior
// chunks' suppressions (vmask) and earlier accepted rows in-chunk (intra) —
// the reference greedy restricted to valid0 members (non-members never act
// since valid only shrinks). Survivors in greedy order == reference output
// order (suppressed rows exact zeros; stable ties).
// ---------------------------------------------------------------------------
__global__ __launch_bounds__(256) void k_greedy(const u32* __restrict__ sidx_ws,
                                                const u64* __restrict__ pvm_ws,
                                                const u32* __restrict__ tcnt,
                                                const u64* __restrict__ adj,
                                                const float* __restrict__ pro,
                                                const float* __restrict__ boxes,
                                                const float* __restrict__ scales,
                                                float* __restrict__ out) {
#pragma clang fp contract(off)
    __shared__ u32 sidx[NPAD_];
    __shared__ u64 srows[2][CH_][NW_];
    __shared__ u64 sintra[CH_];
    __shared__ u64 vmask[NW_];
    __shared__ u64 s_accept;
    __shared__ u32 slist[NPAD_];
    __shared__ u32 s_S;
    const int tid  = threadIdx.x;
    const int lane = tid & 63;
    const int wv   = tid >> 6;
    const int bc   = blockIdx.x;
    const int b    = bc / C_, c = bc % C_;
    const size_t bN = (size_t)b * N_;

    const int T = (int)tcnt[bc];
    for (int x = tid; x < T; x += 256) sidx[x] = sidx_ws[(size_t)bc * N_ + x];
    if (tid < NW_) vmask[tid] = pvm_ws[(size_t)bc * 64 + tid];
    __syncthreads();

    // stage chunk 0
#pragma unroll
    for (int rr = 0; rr < 16; ++rr) {
        const int r = wv * 16 + rr;
        const u32 idx = (r < T) ? sidx[r] : 0u;
        if (lane < NW_) srows[0][r][lane] = adj[(bN + idx) * (size_t)NW_ + lane];
    }
    __syncthreads();

    u32 S = 0;                           // meaningful in wave 0
    const int NCH = (T + CH_ - 1) / CH_;
    for (int ch = 0; ch < NCH; ++ch) {
        const int cur = ch & 1, nxt = cur ^ 1;
        const int c0 = ch * CH_;
        const int cn = min(CH_, T - c0);
        const int havenext = (ch + 1 < NCH);

        // --- phase A: prefetch next chunk rows + intra-chunk masks ---
        u64 pre[16];
#pragma unroll
        for (int rr = 0; rr < 16; ++rr) {
            const int r = wv * 16 + rr;
            const int q = c0 + CH_ + r;
            const u32 idxn = (havenext && q < T) ? sidx[q] : 0u;
            pre[rr] = (havenext && lane < NW_)
                        ? adj[(bN + idxn) * (size_t)NW_ + lane] : 0ull;
        }
#pragma unroll
        for (int rr = 0; rr < 16; ++rr) {
            const int r = wv * 16 + rr;
            const u32 idxr = (c0 + r < T) ? sidx[c0 + r] : 0u;   // uniform/iter
            const u64 rj = srows[cur][lane][idxr >> 6];  // own row, sym. trick
            const u64 ib = __ballot((lane < cn) && ((rj >> (idxr & 63)) & 1ull));
            if (lane == 0) sintra[r] = ib;
        }
        __syncthreads();

        // --- phase B: wave 0 sparse resolve + survivor emit ---
        if (wv == 0) {
            const u32 idxme = (c0 + lane < T) ? sidx[c0 + lane] : 0u;
            const u64 vm = vmask[idxme >> 6];            // LDS scatter read
            u64 cv = __ballot((lane < cn) && ((vm >> (idxme & 63)) & 1ull));
            const u64 iv = sintra[lane];
            const u32 ivLo = (u32)iv, ivHi = (u32)(iv >> 32);
            u64 accept = 0ull;
            while (cv) {
                const int r = __builtin_ctzll(cv);
                accept |= 1ull << r;
                const u64 ir =
                    ((u64)(u32)__builtin_amdgcn_readlane((int)ivHi, r) << 32)
                  |  (u64)(u32)__builtin_amdgcn_readlane((int)ivLo, r);
                cv &= ~(ir | (1ull << r));
            }
            if (lane == 0) s_accept = accept;
            const u32 bitl = (u32)((accept >> lane) & 1ull);
            if (bitl) {
                const u32 pos = S + (u32)__popcll(accept & ((1ull << lane) - 1ull));
                slist[pos] = idxme;
            }
            S += (u32)__popcll(accept);
        }
        __syncthreads();

        // --- phase C: parallel apply + store prefetched rows ---
        const u64 ac = s_accept;
        u64 acc = 0ull;
#pragma unroll
        for (int rr = 0; rr < 16; ++rr) {
            const int r = wv * 16 + rr;
            if ((ac >> r) & 1ull)                        // wave-uniform branch
                acc |= srows[cur][r][min(lane, NW_ - 1)];
        }
        if (lane < NW_ && acc)
            atomicAnd(&vmask[lane], ~acc);
        if (havenext) {
#pragma unroll
            for (int rr = 0; rr < 16; ++rr) {
                const int r = wv * 16 + rr;
                if (lane < NW_) srows[nxt][r][lane] = pre[rr];
            }
        }
        __syncthreads();
    }
    if (wv == 0 && lane == 0) s_S = S;
    __syncthreads();

    // output survivors in greedy order (suppressed rows stay exact zeros)
    const int Sf = (int)s_S;
    const float s = scales[b];
    for (int r = tid; r < Sf; r += 256) {
        const int idx = (int)slist[r];
        const float4 bx = reinterpret_cast<const float4*>(boxes)[bN + idx];
        const float scx = bx.x * s, scy = bx.y * s, sw = bx.z * s, sh = bx.w * s;
        float* o = out + ((size_t)bc * N_ + r) * 5;
        o[0] = scx - 0.5f * sw;
        o[1] = scy - 0.5f * sh;
        o[2] = scx + 0.5f * sw;
        o[3] = scy + 0.5f * sh;
        o[4] = pro[(bN + idx) * C_ + c];
        out[(size_t)B_ * C_ * N_ * 5 + (size_t)bc * N_ + r] = 1.0f;
    }
}

// ---------------------------------------------------------------------------
extern "C" void kernel_launch(void* const* d_in, const int* in_sizes, int n_in,
                              void* d_out, int out_size, void* d_ws, size_t ws_size,
                              hipStream_t stream) {
    const float* pro    = (const float*)d_in[0];   // (B,N,C)
    const float* con    = (const float*)d_in[1];   // (B,N,C)
    const float* boxes  = (const float*)d_in[2];   // (B,N,4)
    const float* scales = (const float*)d_in[3];   // (B,)
    const float* conf   = (const float*)d_in[4];   // (C,)

    char* ws = (char*)d_ws;
    u64* adj = (u64*)ws;                                   // B*N*NW u64  (6.57 MB)
    size_t off = (size_t)B_ * N_ * NW_ * sizeof(u64);
    float* thr = (float*)(ws + off);                       // B*N*C f32   (0.92 MB)
    off += (size_t)B_ * N_ * C_ * sizeof(float);
    u32* sidx_ws = (u32*)(ws + off);                       // B*C*N u32   (0.92 MB)
    off += (size_t)B_ * C_ * N_ * sizeof(u32);
    u64* pvm_ws = (u64*)(ws + off);                        // 64*64 u64   (32 KB)
    off += (size_t)B_ * C_ * 64 * sizeof(u64);
    u32* tcnt = (u32*)(ws + off);                          // 64 u32

    hipMemsetAsync(d_out, 0, (size_t)out_size * sizeof(float), stream);
    k_adjcon<<<B_ * N_ / RPB_, 256, 0, stream>>>(boxes, con, adj, thr);
    k_prep  <<<B_ * C_,        256, 0, stream>>>(pro, thr, conf, sidx_ws, pvm_ws, tcnt);
    k_greedy<<<B_ * C_,        256, 0, stream>>>(sidx_ws, pvm_ws, tcnt, adj, pro,
                                                 boxes, scales, (float*)d_out);
}